// Round 1
// baseline (77.715 us; speedup 1.0000x reference)
//
#include <hip/hip_runtime.h>
#include <math.h>

#define DIM 128
#define WIN 128
#define SEQ 2048
#define NEG_INF -1.0e9f

__global__ __launch_bounds__(256) void swa_fwd_kernel(
    const float* __restrict__ q,
    const float* __restrict__ k,
    const float* __restrict__ v,
    float* __restrict__ out) {
  const int lane = threadIdx.x & 63;
  const int wave = threadIdx.x >> 6;
  const int row  = blockIdx.x * 4 + wave;   // global query index in [0, B*S)
  const int b = row >> 11;                  // / 2048
  const int s = row & 2047;                 // % 2048

  const float* __restrict__ qrow = q + (size_t)row * DIM;
  const float* __restrict__ kb   = k + (size_t)b * SEQ * DIM;
  const float* __restrict__ vb   = v + (size_t)b * SEQ * DIM;

  // window positions handled by this lane: j0 = lane, j1 = lane + 64, j2 = 128 (all lanes)
  const int idx0 = s - WIN + lane;
  const int idx1 = s - 64  + lane;
  const int i0 = idx0 < 0 ? 0 : idx0;
  const int i1 = idx1 < 0 ? 0 : idx1;
  const float* __restrict__ k0 = kb + (size_t)i0 * DIM;
  const float* __restrict__ k1 = kb + (size_t)i1 * DIM;
  const float* __restrict__ k2 = kb + (size_t)s  * DIM;   // j = 128, idx = s (always valid)

  float a0 = 0.f, a1 = 0.f, a2 = 0.f;
#pragma unroll 8
  for (int d = 0; d < DIM; d += 4) {
    const float4 qv  = *(const float4*)(qrow + d);
    const float4 k0v = *(const float4*)(k0 + d);
    const float4 k1v = *(const float4*)(k1 + d);
    const float4 k2v = *(const float4*)(k2 + d);
    a0 += qv.x * k0v.x + qv.y * k0v.y + qv.z * k0v.z + qv.w * k0v.w;
    a1 += qv.x * k1v.x + qv.y * k1v.y + qv.z * k1v.z + qv.w * k1v.w;
    a2 += qv.x * k2v.x + qv.y * k2v.y + qv.z * k2v.z + qv.w * k2v.w;
  }
  const float scale = 0.08838834764831845f;  // 128^-0.5
  const float sc0 = (idx0 >= 0) ? a0 * scale : NEG_INF;
  const float sc1 = (idx1 >= 0) ? a1 * scale : NEG_INF;
  const float sc2 = a2 * scale;

  // wave-wide max over 129 scores
  float m = fmaxf(fmaxf(sc0, sc1), sc2);
#pragma unroll
  for (int off = 1; off < 64; off <<= 1) m = fmaxf(m, __shfl_xor(m, off));

  const float p0 = __expf(sc0 - m);
  const float p1 = __expf(sc1 - m);
  const float p2 = __expf(sc2 - m);   // identical across lanes

  float sum = p0 + p1;
#pragma unroll
  for (int off = 1; off < 64; off <<= 1) sum += __shfl_xor(sum, off);
  sum += p2;                          // j=128 counted exactly once
  const float inv = 1.0f / sum;

  // PV: lane owns output dims (lane) and (lane + 64)
  float acca = 0.f, accb = 0.f;
  for (int j = 0; j < 64; ++j) {
    const int idx = s - WIN + j;
    if (idx >= 0) {                   // wave-uniform branch
      const float pj = __shfl(p0, j);
      acca += pj * vb[(size_t)idx * DIM + lane];
      accb += pj * vb[(size_t)idx * DIM + 64 + lane];
    }
  }
  for (int j = 0; j < 64; ++j) {
    const int idx = s - 64 + j;
    if (idx >= 0) {                   // wave-uniform branch
      const float pj = __shfl(p1, j);
      acca += pj * vb[(size_t)idx * DIM + lane];
      accb += pj * vb[(size_t)idx * DIM + 64 + lane];
    }
  }
  acca += p2 * vb[(size_t)s * DIM + lane];
  accb += p2 * vb[(size_t)s * DIM + 64 + lane];

  out[(size_t)row * DIM + lane]      = acca * inv;
  out[(size_t)row * DIM + 64 + lane] = accb * inv;
}

extern "C" void kernel_launch(void* const* d_in, const int* in_sizes, int n_in,
                              void* d_out, int out_size, void* d_ws, size_t ws_size,
                              hipStream_t stream) {
  const float* q = (const float*)d_in[0];
  const float* k = (const float*)d_in[1];
  const float* v = (const float*)d_in[2];
  float* out = (float*)d_out;
  // B*S = 4096 query rows, 1 wave each, 4 waves per block
  dim3 grid(1024), block(256);
  swa_fwd_kernel<<<grid, block, 0, stream>>>(q, k, v, out);
}

// Round 2
// 13.477 us; speedup vs baseline: 5.7665x; 5.7665x over previous
//
#include <hip/hip_runtime.h>
#include <math.h>

#define SEQ 2048
#define DIME 128
#define BQ 16
#define NEG_INF -1.0e9f

typedef __attribute__((ext_vector_type(8))) short bf16x8;
typedef __attribute__((ext_vector_type(4))) float f32x4;

// f32 -> bf16 (round-nearest-even)
static __device__ __forceinline__ short f2b(float x) {
  union { float f; unsigned u; } v; v.f = x;
  unsigned r = v.u + 0x7FFF + ((v.u >> 16) & 1);
  return (short)(r >> 16);
}

// One PV chunk of 32 window-keys: builds the P fragment (A operand) from the
// score registers via shfl, loads V fragments (B operand), accumulates o[8].
// Window keys covered: kglob = kget0 + 8*g + j (assumed k-slot mapping; any
// permutation is applied identically to A and B so the MFMA sum is exact).
template<bool HAS_HI>
static __device__ __forceinline__ void pv_chunk(
    const float (&pLo)[4], const float (&pHi)[4],
    const float* __restrict__ vb, int kget0, int col, int g,
    f32x4 (&o)[8]) {
  bf16x8 pa;
#pragma unroll
  for (int j = 0; j < 8; ++j) {
    const int r = j & 3;
    const int src = (2 * (g & 1) + (j >> 2)) * 16 + col;
    const float plo = __shfl(pLo[r], src);
    float val;
    if (HAS_HI) {
      const float phi = __shfl(pHi[r], src);
      val = (g >= 2) ? phi : plo;
    } else {
      val = (g >= 2) ? 0.0f : plo;
    }
    pa[j] = f2b(val);
  }
#pragma unroll
  for (int dt = 0; dt < 8; ++dt) {
    bf16x8 bv;
#pragma unroll
    for (int j = 0; j < 8; ++j) {
      int kg = kget0 + 8 * g + j;
      kg = kg < 0 ? 0 : (kg > SEQ - 1 ? SEQ - 1 : kg);
      bv[j] = f2b(vb[(size_t)kg * DIME + 16 * dt + col]);
    }
    o[dt] = __builtin_amdgcn_mfma_f32_16x16x32_bf16(pa, bv, o[dt], 0, 0, 0);
  }
}

__global__ __launch_bounds__(256) void swa_mfma_kernel(
    const float* __restrict__ q, const float* __restrict__ k,
    const float* __restrict__ v, float* __restrict__ out) {
  __shared__ float lds_m[4][16];
  __shared__ float lds_s[4][16];
  __shared__ float lds_o[4][16][132];   // +4 pad: write conflicts -> 2-way (free)

  const int tid = threadIdx.x;
  const int lane = tid & 63;
  const int w = tid >> 6;      // wave id 0..3
  const int col = lane & 15;
  const int g = lane >> 4;

  const int blk = blockIdx.x;  // 256 blocks: 128 q-tiles x 2 batches
  const int b = blk >> 7;
  const int qs = (blk & 127) * BQ;
  const int kbase = qs - 128;  // global key index of window position 0

  const float* __restrict__ qb = q + (size_t)b * SEQ * DIME;
  const float* __restrict__ kb = k + (size_t)b * SEQ * DIME;
  const float* __restrict__ vb = v + (size_t)b * SEQ * DIME;

  // ---- Q fragments (B operand): lane holds Q[qs+col][32*kc + 8*g + j] ----
  bf16x8 qf[4];
  {
    const float* qrow = qb + (size_t)(qs + col) * DIME + 8 * g;
#pragma unroll
    for (int kc = 0; kc < 4; ++kc) {
      const float4 lo = *(const float4*)(qrow + 32 * kc);
      const float4 hi = *(const float4*)(qrow + 32 * kc + 4);
      bf16x8 f;
      f[0] = f2b(lo.x); f[1] = f2b(lo.y); f[2] = f2b(lo.z); f[3] = f2b(lo.w);
      f[4] = f2b(hi.x); f[5] = f2b(hi.y); f[6] = f2b(hi.z); f[7] = f2b(hi.w);
      qf[kc] = f;
    }
  }

  // ---- S phase: S^T tiles (C layout: row=key_local=(g*4+r), col=query) ----
  // wave w owns window tiles {2w, 2w+1}; tile 8 computed by all (masked for w>0)
  float sc[3][4];
  const float scale = 0.08838834764831845f;  // 128^-0.5
#pragma unroll
  for (int ti = 0; ti < 3; ++ti) {
    const int t = (ti == 2) ? 8 : 2 * w + ti;
    f32x4 acc = {0.f, 0.f, 0.f, 0.f};
    const int krow = kbase + 16 * t + col;
    const float* krp = kb + (size_t)(krow < 0 ? 0 : krow) * DIME + 8 * g;
#pragma unroll
    for (int kc = 0; kc < 4; ++kc) {
      const float4 lo = *(const float4*)(krp + 32 * kc);
      const float4 hi = *(const float4*)(krp + 32 * kc + 4);
      bf16x8 a;
      a[0] = f2b(lo.x); a[1] = f2b(lo.y); a[2] = f2b(lo.z); a[3] = f2b(lo.w);
      a[4] = f2b(hi.x); a[5] = f2b(hi.y); a[6] = f2b(hi.z); a[7] = f2b(hi.w);
      acc = __builtin_amdgcn_mfma_f32_16x16x32_bf16(a, qf[kc], acc, 0, 0, 0);
    }
#pragma unroll
    for (int r = 0; r < 4; ++r) {
      const int kg = kbase + 16 * t + 4 * g + r;
      const int qg = qs + col;
      const bool valid = (kg >= 0) && (kg >= qg - 128) && (kg <= qg) &&
                         (ti != 2 || w == 0);
      sc[ti][r] = valid ? acc[r] * scale : NEG_INF;
    }
  }

  // ---- local (per-wave) softmax over this wave's keys; per query column ----
  float m = NEG_INF;
#pragma unroll
  for (int ti = 0; ti < 3; ++ti)
#pragma unroll
    for (int r = 0; r < 4; ++r) m = fmaxf(m, sc[ti][r]);
  m = fmaxf(m, __shfl_xor(m, 16));
  m = fmaxf(m, __shfl_xor(m, 32));
  float s = 0.f;
#pragma unroll
  for (int ti = 0; ti < 3; ++ti)
#pragma unroll
    for (int r = 0; r < 4; ++r) {
      const float p = __expf(sc[ti][r] - m);
      sc[ti][r] = p;
      s += p;
    }
  s += __shfl_xor(s, 16);
  s += __shfl_xor(s, 32);
  if (lane < 16) { lds_m[w][lane] = m; lds_s[w][lane] = s; }

  // ---- PV: wave w does window-key chunk [32w,32w+32); wave 0 also [128,160)
  f32x4 o[8];
#pragma unroll
  for (int dt = 0; dt < 8; ++dt) o[dt] = (f32x4){0.f, 0.f, 0.f, 0.f};
  pv_chunk<true>(sc[0], sc[1], vb, kbase + 32 * w, col, g, o);
  if (w == 0) pv_chunk<false>(sc[2], sc[2], vb, kbase + 128, col, g, o);

  __syncthreads();  // stats visible

  // ---- scale own partial O by exp(m_w - M) and stage in LDS ----
  // O C-layout: lane holds O[q_local = 4*g + r][16*dt + col]
#pragma unroll
  for (int r = 0; r < 4; ++r) {
    const int ql = 4 * g + r;
    float M = lds_m[0][ql];
    M = fmaxf(M, lds_m[1][ql]);
    M = fmaxf(M, lds_m[2][ql]);
    M = fmaxf(M, lds_m[3][ql]);
    const float wgt = __expf(lds_m[w][ql] - M);
#pragma unroll
    for (int dt = 0; dt < 8; ++dt)
      lds_o[w][ql][16 * dt + col] = o[dt][r] * wgt;
  }
  __syncthreads();

  // ---- reduce 4 partials + normalize + store (256 threads x 8 floats) ----
  {
    const int f = tid * 8;
    const int ql = f >> 7;
    const int d0 = f & 127;
    float M = lds_m[0][ql];
    M = fmaxf(M, lds_m[1][ql]);
    M = fmaxf(M, lds_m[2][ql]);
    M = fmaxf(M, lds_m[3][ql]);
    float St = 0.f;
#pragma unroll
    for (int ww = 0; ww < 4; ++ww)
      St += lds_s[ww][ql] * __expf(lds_m[ww][ql] - M);
    const float inv = 1.0f / St;
    f32x4 acc0 = {0.f, 0.f, 0.f, 0.f}, acc1 = {0.f, 0.f, 0.f, 0.f};
#pragma unroll
    for (int ww = 0; ww < 4; ++ww) {
      acc0 += *(const f32x4*)&lds_o[ww][ql][d0];
      acc1 += *(const f32x4*)&lds_o[ww][ql][d0 + 4];
    }
    acc0 *= inv;
    acc1 *= inv;
    float* op = out + (size_t)(b * SEQ + qs + ql) * DIME + d0;
    *(f32x4*)op = acc0;
    *(f32x4*)(op + 4) = acc1;
  }
}

extern "C" void kernel_launch(void* const* d_in, const int* in_sizes, int n_in,
                              void* d_out, int out_size, void* d_ws, size_t ws_size,
                              hipStream_t stream) {
  const float* q = (const float*)d_in[0];
  const float* k = (const float*)d_in[1];
  const float* v = (const float*)d_in[2];
  float* out = (float*)d_out;
  // 2 batches x 128 q-tiles of 16 queries = 256 blocks, 4 waves each
  dim3 grid(256), block(256);
  swa_mfma_kernel<<<grid, block, 0, stream>>>(q, k, v, out);
}